// Round 4
// baseline (252.743 us; speedup 1.0000x reference)
//
#include <hip/hip_runtime.h>

// DilatedReparamBlock folded into one 13x13 depthwise conv + bias.
//
// R4 structure: block = 128 threads (2 waves) = 1 plane (56x56).
// Thread patch = 7 rows x 4 cols (xg 0..13, yg 0..7; 112 active lanes).
// LDS 19.4KB/block -> 8 blocks/CU = 16 waves/CU = 4 waves/SIMD (R3 was 2:
// latency-bound, VALUBusy 48%). ky-quad register rolling: each staged row
// is ds_read once and serves 4 ky taps (weights for the quad broadcast
// from a stride-13 LDS array into VGPRs once per group).
// Note (R3 lesson): SQ_LDS_BANK_CONFLICT ~11/instr is structural for
// ds_read_b128 (256 words / 32 banks = 8-deep serialization) — not
// address-fixable; the lever is occupancy + fewer LDS instructions.

#define CCH 384
#define SP 56
#define PW 68              // 56 + 2*6 padding
#define NPLANES (16*384)
#define BLK 128

__global__ __launch_bounds__(BLK, 4) void drb_conv13_2w(
    const float* __restrict__ x,
    const float* __restrict__ w_lk, const float* __restrict__ w_b0,
    const float* __restrict__ w_b1, const float* __restrict__ w_b2,
    const float* __restrict__ w_b3, const float* __restrict__ w_b4,
    const float* __restrict__ w_b5,
    const float* __restrict__ gamma, const float* __restrict__ beta,
    const float* __restrict__ mean, const float* __restrict__ var,
    float* __restrict__ out)
{
    __shared__ __align__(16) float sx[PW * PW];   // 18496 B padded plane
    __shared__ __align__(16) float sw[176];       // merged 13x13, stride 13

    const int plane = blockIdx.x;                 // n*384 + c
    const int c = plane % CCH;
    const int tid = threadIdx.x;
    const float* __restrict__ xp = x + (size_t)plane * (SP * SP);

    // --- BN fold constants ---
    float S[7];
    float bias = 0.f;
    #pragma unroll
    for (int j = 0; j < 7; j++) {
        float inv = gamma[j * CCH + c] * rsqrtf(var[j * CCH + c] + 1e-5f);
        S[j] = inv;
        bias += beta[j * CCH + c] - mean[j * CCH + c] * inv;
    }

    // --- zero padded tile (b128 stores) ---
    {
        float4 z = make_float4(0.f, 0.f, 0.f, 0.f);
        #pragma unroll
        for (int k = 0; k < 10; k++) {
            int i = tid + BLK * k;
            if (i < PW * PW / 4) ((float4*)sx)[i] = z;
        }
    }
    __syncthreads();   // zero (whole tile) must precede interior staging

    // --- build merged 13x13 weights, flat stride-13 layout ---
    #pragma unroll
    for (int k = 0; k < 2; k++) {
        int t = tid + BLK * k;
        if (t < 169) {
            int ky = t / 13, kx = t - 13 * ky;
            float w = S[0] * w_lk[c * 169 + t];                            // 13x13 d1
            if (ky >= 4 && ky <= 8 && kx >= 4 && kx <= 8)                  // 5x5 d1 @4
                w += S[1] * w_b0[c * 25 + (ky - 4) * 5 + (kx - 4)];
            if (ky >= 3 && ky <= 9 && kx >= 3 && kx <= 9)                  // 7x7 d1 @3
                w += S[2] * w_b1[c * 49 + (ky - 3) * 7 + (kx - 3)];
            if (!(ky & 1) && !(kx & 1))                                    // 7x7 d2
                w += S[3] * w_b2[c * 49 + (ky >> 1) * 7 + (kx >> 1)];
            if (ky >= 3 && ky <= 9 && (ky - 3) % 3 == 0 &&
                kx >= 3 && kx <= 9 && (kx - 3) % 3 == 0)                   // 3x3 d3
                w += S[4] * w_b3[c * 9 + ((ky - 3) / 3) * 3 + (kx - 3) / 3];
            if (ky >= 2 && ky <= 10 && (ky - 2) % 4 == 0 &&
                kx >= 2 && kx <= 10 && (kx - 2) % 4 == 0)                  // 3x3 d4
                w += S[5] * w_b4[c * 9 + ((ky - 2) / 4) * 3 + (kx - 2) / 4];
            if (ky >= 1 && ky <= 11 && (ky - 1) % 5 == 0 &&
                kx >= 1 && kx <= 11 && (kx - 1) % 5 == 0)                  // 3x3 d5
                w += S[6] * w_b5[c * 9 + ((ky - 1) / 5) * 3 + (kx - 1) / 5];
            sw[t] = w;
        }
    }

    // --- stage plane interior: 784 float4 loads ---
    #pragma unroll
    for (int k = 0; k < 7; k++) {
        int i4 = tid + BLK * k;
        if (i4 < SP * SP / 4) {
            float4 v = ((const float4*)xp)[i4];
            int r = i4 / 14;                 // 14 float4 per 56-wide row
            int col = (i4 - r * 14) * 4;
            float* d = &sx[(r + 6) * PW + col + 6];   // 8B aligned
            ((float2*)d)[0] = make_float2(v.x, v.y);
            ((float2*)d)[1] = make_float2(v.z, v.w);
        }
    }
    __syncthreads();

    // --- compute: lane (xg,yg) -> rows [7yg..7yg+6], cols [4xg..4xg+3] ---
    const int tact = (tid < 112) ? tid : 0;   // idle lanes shadow lane 0 (broadcast)
    const int xg = tact % 14;
    const int yg = tact / 14;
    const int Yb = yg * 7;
    const float* __restrict__ sbase = &sx[Yb * PW + 4 * xg];

    float acc[7][4];
    #pragma unroll
    for (int r = 0; r < 7; r++)
        #pragma unroll
        for (int j = 0; j < 4; j++) acc[r][j] = 0.f;

    // ky quads {0-3},{4-7},{8-11}: input rows k0..k0+9, row i serves
    // (r = i-d, ky = k0+d) for d in 0..3, 0<=r<=6.
    #pragma unroll 1
    for (int g = 0; g < 3; g++) {
        const int k0 = g * 4;
        float4 wq[13];                        // 52 quad weights -> VGPRs
        #pragma unroll
        for (int q = 0; q < 13; q++)
            wq[q] = ((const float4*)&sw[k0 * 13])[q];
        const float* w = (const float*)wq;
        const float* sr = sbase + k0 * PW;
        #pragma unroll
        for (int i = 0; i < 10; i++) {
            float4 win4[4];
            #pragma unroll
            for (int q = 0; q < 4; q++)
                win4[q] = *(const float4*)(sr + i * PW + 4 * q);
            const float* win = (const float*)win4;
            #pragma unroll
            for (int d = 0; d < 4; d++) {
                const int r = i - d;
                if (r >= 0 && r <= 6) {
                    #pragma unroll
                    for (int kx = 0; kx < 13; kx++) {
                        const float wv = w[d * 13 + kx];
                        #pragma unroll
                        for (int j = 0; j < 4; j++)
                            acc[r][j] = fmaf(wv, win[kx + j], acc[r][j]);
                    }
                }
            }
        }
    }
    // tail ky = 12: rows Yb+12 .. Yb+18
    {
        float wt[13];
        #pragma unroll
        for (int q = 0; q < 3; q++)
            ((float4*)wt)[q] = ((const float4*)&sw[156])[q];
        wt[12] = sw[168];
        const float* sr = sbase + 12 * PW;
        #pragma unroll
        for (int r = 0; r < 7; r++) {
            float4 win4[4];
            #pragma unroll
            for (int q = 0; q < 4; q++)
                win4[q] = *(const float4*)(sr + r * PW + 4 * q);
            const float* win = (const float*)win4;
            #pragma unroll
            for (int kx = 0; kx < 13; kx++) {
                const float wv = wt[kx];
                #pragma unroll
                for (int j = 0; j < 4; j++)
                    acc[r][j] = fmaf(wv, win[kx + j], acc[r][j]);
            }
        }
    }

    // --- epilogue ---
    if (tid < 112) {
        float* op = out + (size_t)plane * (SP * SP) + Yb * SP + 4 * xg;
        #pragma unroll
        for (int r = 0; r < 7; r++) {
            float4 v = make_float4(acc[r][0] + bias, acc[r][1] + bias,
                                   acc[r][2] + bias, acc[r][3] + bias);
            *(float4*)(op + r * SP) = v;
        }
    }
}

extern "C" void kernel_launch(void* const* d_in, const int* in_sizes, int n_in,
                              void* d_out, int out_size, void* d_ws, size_t ws_size,
                              hipStream_t stream) {
    const float* x    = (const float*)d_in[0];
    const float* w_lk = (const float*)d_in[1];
    const float* w_b0 = (const float*)d_in[2];
    const float* w_b1 = (const float*)d_in[3];
    const float* w_b2 = (const float*)d_in[4];
    const float* w_b3 = (const float*)d_in[5];
    const float* w_b4 = (const float*)d_in[6];
    const float* w_b5 = (const float*)d_in[7];
    const float* bn_g = (const float*)d_in[8];
    const float* bn_b = (const float*)d_in[9];
    const float* bn_m = (const float*)d_in[10];
    const float* bn_v = (const float*)d_in[11];
    float* out = (float*)d_out;

    drb_conv13_2w<<<dim3(NPLANES), dim3(BLK), 0, stream>>>(
        x, w_lk, w_b0, w_b1, w_b2, w_b3, w_b4, w_b5,
        bn_g, bn_b, bn_m, bn_v, out);
}